// Round 5
// baseline (288.815 us; speedup 1.0000x reference)
//
#include <hip/hip_runtime.h>

typedef unsigned short u16;
typedef unsigned short u16x4 __attribute__((ext_vector_type(4), may_alias));
typedef unsigned short u16x8 __attribute__((ext_vector_type(8), may_alias));
typedef __bf16 bf16x8 __attribute__((ext_vector_type(8), may_alias));
typedef float f32x4 __attribute__((ext_vector_type(4), may_alias));

typedef __attribute__((address_space(1))) void gvoid_t;
typedef __attribute__((address_space(3))) void lvoid_t;

__device__ __forceinline__ void gld16(const void* g, void* l) {
    __builtin_amdgcn_global_load_lds((gvoid_t*)g, (lvoid_t*)l, 16, 0, 0);
}

__device__ __forceinline__ u16 f2bf(float f) {
    unsigned u = __builtin_bit_cast(unsigned, f);
    u += 0x7fffu + ((u >> 16) & 1u);
    return (u16)(u >> 16);
}

#define KSCALE 0.18033688011112042f  /* 0.125 * log2(e) */

// ---------------- fp32 -> bf16 elementwise ----------------
__global__ __launch_bounds__(256) void cvt_f32_bf16_k(const float* __restrict__ in,
                                                      u16* __restrict__ out, int n8) {
    int i = blockIdx.x * 256 + threadIdx.x;
    if (i >= n8) return;
    float4 a = reinterpret_cast<const float4*>(in)[2 * i];
    float4 c = reinterpret_cast<const float4*>(in)[2 * i + 1];
    u16x8 o;
    o[0] = f2bf(a.x); o[1] = f2bf(a.y); o[2] = f2bf(a.z); o[3] = f2bf(a.w);
    o[4] = f2bf(c.x); o[5] = f2bf(c.y); o[6] = f2bf(c.z); o[7] = f2bf(c.w);
    reinterpret_cast<u16x8*>(out)[i] = o;
}

// ---------------- fp32 [R][C] -> bf16 [C][R] transpose ----------------
__global__ __launch_bounds__(256) void tr_f32_bf16_k(const float* __restrict__ in,
                                                     u16* __restrict__ out, int R, int C) {
    __shared__ u16 t[64][73];
    int tc = C >> 6;
    int r0 = (blockIdx.x / tc) << 6, c0 = (blockIdx.x % tc) << 6;
    int lr = threadIdx.x >> 2;
    int lc = (threadIdx.x & 3) << 4;
    const float* src = in + (size_t)(r0 + lr) * C + c0 + lc;
#pragma unroll
    for (int j = 0; j < 16; j += 4) {
        float4 v = *reinterpret_cast<const float4*>(src + j);
        t[lr][lc + j + 0] = f2bf(v.x);
        t[lr][lc + j + 1] = f2bf(v.y);
        t[lr][lc + j + 2] = f2bf(v.z);
        t[lr][lc + j + 3] = f2bf(v.w);
    }
    __syncthreads();
    u16x8 o0, o1;
#pragma unroll
    for (int j = 0; j < 8; j++) { o0[j] = t[lc + j][lr]; o1[j] = t[lc + 8 + j][lr]; }
    u16* dst = out + (size_t)(c0 + lr) * R + r0 + lc;
    *reinterpret_cast<u16x8*>(dst) = o0;
    *reinterpret_cast<u16x8*>(dst + 8) = o1;
}

// ---------------- bf16 GEMM: C = A[M][K] * Bt[N][K]^T + bias ----------------
template <int MODE>
__global__ __launch_bounds__(256) void gemm_bt_k(const u16* __restrict__ A,
                                                 const u16* __restrict__ Bt,
                                                 const float* __restrict__ bias,
                                                 u16* __restrict__ Qp, u16* __restrict__ Kp,
                                                 u16* __restrict__ Vt,
                                                 float* __restrict__ Cf,
                                                 int M, int N, int K) {
    __shared__ u16 As[2][128 * 64];
    __shared__ u16 Bs[2][128 * 64];
    const int tid = threadIdx.x;
    const int l = tid & 63, w = tid >> 6;
    const int wm = w >> 1, wn = w & 1;
    const int l16 = l & 15, lg = l >> 4;
    const int tc = N >> 7;
    const int bm = blockIdx.x / tc, bn = blockIdx.x % tc;
    const u16* Ab = A + (size_t)(bm << 7) * K;
    const u16* Bb = Bt + (size_t)(bn << 7) * K;

    f32x4 acc[4][4];
#pragma unroll
    for (int mi = 0; mi < 4; mi++)
#pragma unroll
        for (int ni = 0; ni < 4; ni++)
#pragma unroll
            for (int q = 0; q < 4; q++) acc[mi][ni][q] = 0.f;

    auto stage = [&](int buf, int k0) {
#pragma unroll
        for (int i = 0; i < 4; i++) {
            int s = tid + (i << 8);
            int ub = ((i << 8) + (w << 6)) << 3;
            gld16(Ab + (size_t)(s >> 3) * K + k0 + ((s & 7) << 3), &As[buf][ub]);
            gld16(Bb + (size_t)(s >> 3) * K + k0 + ((s & 7) << 3), &Bs[buf][ub]);
        }
    };

    stage(0, 0);
    int cur = 0;
    for (int k0 = 0; k0 < K; k0 += 64) {
        __syncthreads();
        if (k0 + 64 < K) stage(cur ^ 1, k0 + 64);
        const u16* Asc = As[cur];
        const u16* Bsc = Bs[cur];
#pragma unroll
        for (int kk = 0; kk < 2; kk++) {
            bf16x8 af[4], bfr[4];
#pragma unroll
            for (int mi = 0; mi < 4; mi++)
                af[mi] = *reinterpret_cast<const bf16x8*>(
                    &Asc[((wm << 6) + (mi << 4) + l16) * 64 + (kk << 5) + (lg << 3)]);
#pragma unroll
            for (int ni = 0; ni < 4; ni++)
                bfr[ni] = *reinterpret_cast<const bf16x8*>(
                    &Bsc[((wn << 6) + (ni << 4) + l16) * 64 + (kk << 5) + (lg << 3)]);
#pragma unroll
            for (int mi = 0; mi < 4; mi++)
#pragma unroll
                for (int ni = 0; ni < 4; ni++)
                    acc[mi][ni] = __builtin_amdgcn_mfma_f32_16x16x32_bf16(af[mi], bfr[ni], acc[mi][ni], 0, 0, 0);
        }
        cur ^= 1;
    }

    const int rb = (bm << 7) + (wm << 6), cb = (bn << 7) + (wn << 6);
    if constexpr (MODE == 0) {
        const int sec = cb >> 10;
#pragma unroll
        for (int ni = 0; ni < 4; ni++) {
            const int col = cb + (ni << 4) + l16;
            const float bb = bias[col];
            const int d = col & 1023, h = d >> 6, dh = d & 63;
#pragma unroll
            for (int mi = 0; mi < 4; mi++) {
                const int row0 = rb + (mi << 4) + (lg << 2);
                const int bidx = row0 >> 11, n0 = row0 & 2047;
                const size_t base = (size_t)(bidx * 16 + h) * 131072;
                if (sec == 0) {
#pragma unroll
                    for (int r = 0; r < 4; r++)
                        Qp[base + (size_t)(n0 + r) * 64 + dh] = f2bf(acc[mi][ni][r] + bb);
                } else if (sec == 1) {
#pragma unroll
                    for (int r = 0; r < 4; r++)
                        Kp[base + (size_t)(n0 + r) * 64 + dh] = f2bf((acc[mi][ni][r] + bb) * KSCALE);
                } else {
                    u16x4 pk;
#pragma unroll
                    for (int r = 0; r < 4; r++) pk[r] = f2bf(acc[mi][ni][r] + bb);
                    *reinterpret_cast<u16x4*>(&Vt[base + (size_t)dh * 2048 + n0]) = pk;
                }
            }
        }
    } else {
#pragma unroll
        for (int ni = 0; ni < 4; ni++) {
            const int col = cb + (ni << 4) + l16;
            const float bb = bias[col];
#pragma unroll
            for (int mi = 0; mi < 4; mi++)
#pragma unroll
                for (int r = 0; r < 4; r++) {
                    const int row = rb + (mi << 4) + (lg << 2) + r;
                    Cf[(size_t)row * N + col] = acc[mi][ni][r] + bb;
                }
        }
    }
}

// ---------------- flash attention: uniform-work 2-wave blocks ----------------
// Block = (bh, x): processes qt=x then qt=63-x (nt(x)+nt(63-x)=33 kv-tiles, exactly
// uniform across ALL blocks). Each qt's kv-range is split contiguously across the
// 2 waves (wave1 owns the tail incl. diagonal); 2-way LDS merge per qt.
__global__ __launch_bounds__(128, 4) void attn_k(const u16* __restrict__ Qp,
                                                 const u16* __restrict__ Kp,
                                                 const u16* __restrict__ Vt,
                                                 u16* __restrict__ Y) {
    __shared__ u16 P_lds[2][32 * 72];
    __shared__ float Obuf[32][68];
    __shared__ float Ml[2][2][16][2];
    const int tid = threadIdx.x;
    const int l = tid & 63, w = tid >> 6;       // w in {0,1}
    const int l16 = l & 15, lg = l >> 4;
    const int x  = blockIdx.x >> 6;             // 0..31
    const int bh = blockIdx.x & 63;
    const int b = bh >> 4, h = bh & 15;
    const u16* Qb = Qp + (size_t)bh * 131072;
    const u16* Kb = Kp + (size_t)bh * 131072;
    const u16* Vb = Vt + (size_t)bh * 131072;
    u16* pl = &P_lds[w][0];

    for (int half = 0; half < 2; half++) {
        const int qt = half ? (63 - x) : x;
        const int nt = (qt >> 1) + 1;
        const int t0 = w ? (nt >> 1) : 0;
        const int t1 = w ? nt : (nt >> 1);

        bf16x8 qf[2][2];
#pragma unroll
        for (int mi = 0; mi < 2; mi++)
#pragma unroll
            for (int kk = 0; kk < 2; kk++)
                qf[mi][kk] = *reinterpret_cast<const bf16x8*>(
                    Qb + (size_t)(qt * 32 + mi * 16 + l16) * 64 + kk * 32 + lg * 8);

        f32x4 o[2][4];
        float m_s[2] = {-1e30f, -1e30f};
        float l_s[2] = {0.f, 0.f};
#pragma unroll
        for (int mi = 0; mi < 2; mi++)
#pragma unroll
            for (int n = 0; n < 4; n++)
#pragma unroll
                for (int r = 0; r < 4; r++) o[mi][n][r] = 0.f;

        for (int it = t0; it < t1; it++) {
            const int kv0 = it << 6;
            const bool diag = (it == nt - 1);
            bf16x8 kf[4][2];
#pragma unroll
            for (int t = 0; t < 4; t++)
#pragma unroll
                for (int kk = 0; kk < 2; kk++)
                    kf[t][kk] = *reinterpret_cast<const bf16x8*>(
                        Kb + (size_t)(kv0 + t * 16 + l16) * 64 + kk * 32 + lg * 8);

#pragma unroll
            for (int mi = 0; mi < 2; mi++) {
                float s4[4][4];   // S^T: lane owns q-row (mi*16+l16); kv = kv0+t*16+lg*4+r
#pragma unroll
                for (int t = 0; t < 4; t++) {
                    f32x4 s;
                    s[0] = s[1] = s[2] = s[3] = 0.f;
                    s = __builtin_amdgcn_mfma_f32_16x16x32_bf16(kf[t][0], qf[mi][0], s, 0, 0, 0);
                    s = __builtin_amdgcn_mfma_f32_16x16x32_bf16(kf[t][1], qf[mi][1], s, 0, 0, 0);
#pragma unroll
                    for (int r = 0; r < 4; r++) s4[t][r] = s[r];
                }
                if (diag) {
                    const int qg = qt * 32 + mi * 16 + l16;
                    const int kvb = kv0 + lg * 4;
#pragma unroll
                    for (int t = 0; t < 4; t++)
#pragma unroll
                        for (int r = 0; r < 4; r++)
                            if (kvb + t * 16 + r > qg) s4[t][r] = -1e30f;
                }
                float mt[4];
#pragma unroll
                for (int t = 0; t < 4; t++)
                    mt[t] = fmaxf(fmaxf(s4[t][0], s4[t][1]), fmaxf(s4[t][2], s4[t][3]));
                float mx = fmaxf(fmaxf(mt[0], mt[1]), fmaxf(mt[2], mt[3]));
                mx = fmaxf(mx, __shfl_xor(mx, 16, 64));
                mx = fmaxf(mx, __shfl_xor(mx, 32, 64));
                if (__any(mx - m_s[mi] > 8.0f)) {
                    float mn = fmaxf(m_s[mi], mx);
                    float al = __builtin_amdgcn_exp2f(m_s[mi] - mn);
                    m_s[mi] = mn;
                    l_s[mi] *= al;
#pragma unroll
                    for (int r = 0; r < 4; r++) {
                        float ar = __shfl(al, lg * 4 + r, 64);
#pragma unroll
                        for (int n = 0; n < 4; n++) o[mi][n][r] *= ar;
                    }
                }
#pragma unroll
                for (int t = 0; t < 4; t++)
#pragma unroll
                    for (int r = 0; r < 4; r++)
                        s4[t][r] = __builtin_amdgcn_exp2f(s4[t][r] - m_s[mi]);
                float st[4];
#pragma unroll
                for (int t = 0; t < 4; t++)
                    st[t] = (s4[t][0] + s4[t][1]) + (s4[t][2] + s4[t][3]);
                float sm = (st[0] + st[1]) + (st[2] + st[3]);
                sm += __shfl_xor(sm, 16, 64);
                sm += __shfl_xor(sm, 32, 64);
                l_s[mi] += sm;
#pragma unroll
                for (int t = 0; t < 4; t++) {
                    u16x4 pk;
#pragma unroll
                    for (int r = 0; r < 4; r++) pk[r] = f2bf(s4[t][r]);
                    *reinterpret_cast<u16x4*>(pl + (mi * 16 + l16) * 72 + t * 16 + lg * 4) = pk;
                }
            }
            bf16x8 pa[2][2];
#pragma unroll
            for (int mi = 0; mi < 2; mi++)
#pragma unroll
                for (int kk2 = 0; kk2 < 2; kk2++)
                    pa[mi][kk2] = *reinterpret_cast<const bf16x8*>(
                        pl + (mi * 16 + l16) * 72 + kk2 * 32 + lg * 8);
#pragma unroll
            for (int n = 0; n < 4; n++) {
                const u16* vr = Vb + (size_t)(n * 16 + l16) * 2048 + kv0 + lg * 8;
                bf16x8 v0 = *reinterpret_cast<const bf16x8*>(vr);
                bf16x8 v1 = *reinterpret_cast<const bf16x8*>(vr + 32);
#pragma unroll
                for (int mi = 0; mi < 2; mi++) {
                    o[mi][n] = __builtin_amdgcn_mfma_f32_16x16x32_bf16(pa[mi][0], v0, o[mi][n], 0, 0, 0);
                    o[mi][n] = __builtin_amdgcn_mfma_f32_16x16x32_bf16(pa[mi][1], v1, o[mi][n], 0, 0, 0);
                }
            }
        }

        // ---- 2-wave merge for this qt ----
        if (lg == 0) {
#pragma unroll
            for (int mi = 0; mi < 2; mi++) {
                Ml[w][mi][l16][0] = m_s[mi];
                Ml[w][mi][l16][1] = l_s[mi];
            }
        }
        __syncthreads();
        float sc[2][4], inv[2][4];
#pragma unroll
        for (int mi = 0; mi < 2; mi++)
#pragma unroll
            for (int r = 0; r < 4; r++) {
                const int row16 = lg * 4 + r;
                float m0 = Ml[0][mi][row16][0], m1 = Ml[1][mi][row16][0];
                float mtot = fmaxf(m0, m1);
                float lt = Ml[0][mi][row16][1] * __builtin_amdgcn_exp2f(m0 - mtot)
                         + Ml[1][mi][row16][1] * __builtin_amdgcn_exp2f(m1 - mtot);
                float mw = w ? m1 : m0;
                sc[mi][r] = __builtin_amdgcn_exp2f(mw - mtot);
                inv[mi][r] = 1.0f / lt;
            }
        if (w == 0) {
#pragma unroll
            for (int mi = 0; mi < 2; mi++)
#pragma unroll
                for (int r = 0; r < 4; r++)
#pragma unroll
                    for (int n = 0; n < 4; n++)
                        Obuf[mi * 16 + lg * 4 + r][n * 16 + l16] = o[mi][n][r] * sc[mi][r];
        }
        __syncthreads();
        if (w == 1) {
#pragma unroll
            for (int mi = 0; mi < 2; mi++) {
#pragma unroll
                for (int r = 0; r < 4; r++) {
                    const size_t row = (size_t)(b * 2048 + qt * 32 + mi * 16 + lg * 4 + r);
#pragma unroll
                    for (int n = 0; n < 4; n++) {
                        float y = (Obuf[mi * 16 + lg * 4 + r][n * 16 + l16]
                                   + o[mi][n][r] * sc[mi][r]) * inv[mi][r];
                        Y[row * 1024 + h * 64 + n * 16 + l16] = f2bf(y);
                    }
                }
            }
        }
        __syncthreads();   // Ml/Obuf reused next half
    }
}

extern "C" void kernel_launch(void* const* d_in, const int* in_sizes, int n_in,
                              void* d_out, int out_size, void* d_ws, size_t ws_size,
                              hipStream_t stream) {
    const float* x     = (const float*)d_in[0];
    const float* w_qkv = (const float*)d_in[1];
    const float* b_qkv = (const float*)d_in[2];
    const float* w_o   = (const float*)d_in[3];
    const float* b_o   = (const float*)d_in[4];
    float* out = (float*)d_out;

    u16* ws  = (u16*)d_ws;
    u16* xb  = ws;                 // [8192][1024] x bf16; reused as attention output Y
    u16* wqT = ws + 8388608;       // [3072][1024]
    u16* woT = ws + 11534336;      // [1024][1024]
    u16* Qp  = ws + 12582912;      // [64 bh][2048][64]
    u16* Kp  = ws + 20971520;      // [64 bh][2048][64] (pre-scaled by 0.125*log2e)
    u16* Vt  = ws + 29360128;      // [64 bh][64][2048]

    cvt_f32_bf16_k<<<4096, 256, 0, stream>>>(x, xb, 1048576);
    tr_f32_bf16_k<<<768, 256, 0, stream>>>(w_qkv, wqT, 1024, 3072);
    tr_f32_bf16_k<<<256, 256, 0, stream>>>(w_o, woT, 1024, 1024);
    gemm_bt_k<0><<<1536, 256, 0, stream>>>(xb, wqT, b_qkv, Qp, Kp, Vt, nullptr, 8192, 3072, 1024);
    attn_k<<<2048, 128, 0, stream>>>(Qp, Kp, Vt, xb);
    gemm_bt_k<1><<<512, 256, 0, stream>>>(xb, woT, b_o, nullptr, nullptr, nullptr, out, 8192, 1024, 1024);
}

// Round 6
// 253.300 us; speedup vs baseline: 1.1402x; 1.1402x over previous
//
#include <hip/hip_runtime.h>

typedef unsigned short u16;
typedef unsigned short u16x4 __attribute__((ext_vector_type(4), may_alias));
typedef unsigned short u16x8 __attribute__((ext_vector_type(8), may_alias));
typedef __bf16 bf16x8 __attribute__((ext_vector_type(8), may_alias));
typedef float f32x4 __attribute__((ext_vector_type(4), may_alias));

typedef __attribute__((address_space(1))) void gvoid_t;
typedef __attribute__((address_space(3))) void lvoid_t;

__device__ __forceinline__ void gld16(const void* g, void* l) {
    __builtin_amdgcn_global_load_lds((gvoid_t*)g, (lvoid_t*)l, 16, 0, 0);
}

__device__ __forceinline__ u16 f2bf(float f) {
    unsigned u = __builtin_bit_cast(unsigned, f);
    u += 0x7fffu + ((u >> 16) & 1u);
    return (u16)(u >> 16);
}

__device__ __forceinline__ unsigned cvt_pk_bf16(float lo, float hi) {
    unsigned r;
    asm("v_cvt_pk_bf16_f32 %0, %1, %2" : "=v"(r) : "v"(lo), "v"(hi));
    return r;
}

#define KSCALE 0.18033688011112042f  /* 0.125 * log2(e) */

// ---------------- fp32 -> bf16 elementwise ----------------
__global__ __launch_bounds__(256) void cvt_f32_bf16_k(const float* __restrict__ in,
                                                      u16* __restrict__ out, int n8) {
    int i = blockIdx.x * 256 + threadIdx.x;
    if (i >= n8) return;
    float4 a = reinterpret_cast<const float4*>(in)[2 * i];
    float4 c = reinterpret_cast<const float4*>(in)[2 * i + 1];
    u16x8 o;
    o[0] = f2bf(a.x); o[1] = f2bf(a.y); o[2] = f2bf(a.z); o[3] = f2bf(a.w);
    o[4] = f2bf(c.x); o[5] = f2bf(c.y); o[6] = f2bf(c.z); o[7] = f2bf(c.w);
    reinterpret_cast<u16x8*>(out)[i] = o;
}

// ---------------- fp32 [R][C] -> bf16 [C][R] transpose ----------------
__global__ __launch_bounds__(256) void tr_f32_bf16_k(const float* __restrict__ in,
                                                     u16* __restrict__ out, int R, int C) {
    __shared__ u16 t[64][73];
    int tc = C >> 6;
    int r0 = (blockIdx.x / tc) << 6, c0 = (blockIdx.x % tc) << 6;
    int lr = threadIdx.x >> 2;
    int lc = (threadIdx.x & 3) << 4;
    const float* src = in + (size_t)(r0 + lr) * C + c0 + lc;
#pragma unroll
    for (int j = 0; j < 16; j += 4) {
        float4 v = *reinterpret_cast<const float4*>(src + j);
        t[lr][lc + j + 0] = f2bf(v.x);
        t[lr][lc + j + 1] = f2bf(v.y);
        t[lr][lc + j + 2] = f2bf(v.z);
        t[lr][lc + j + 3] = f2bf(v.w);
    }
    __syncthreads();
    u16x8 o0, o1;
#pragma unroll
    for (int j = 0; j < 8; j++) { o0[j] = t[lc + j][lr]; o1[j] = t[lc + 8 + j][lr]; }
    u16* dst = out + (size_t)(c0 + lr) * R + r0 + lc;
    *reinterpret_cast<u16x8*>(dst) = o0;
    *reinterpret_cast<u16x8*>(dst + 8) = o1;
}

// ---------------- bf16 GEMM: C = A[M][K] * Bt[N][K]^T + bias ----------------
template <int MODE>
__global__ __launch_bounds__(256) void gemm_bt_k(const u16* __restrict__ A,
                                                 const u16* __restrict__ Bt,
                                                 const float* __restrict__ bias,
                                                 u16* __restrict__ Qp, u16* __restrict__ Kp,
                                                 u16* __restrict__ Vt,
                                                 float* __restrict__ Cf,
                                                 int M, int N, int K) {
    __shared__ u16 As[2][128 * 64];
    __shared__ u16 Bs[2][128 * 64];
    const int tid = threadIdx.x;
    const int l = tid & 63, w = tid >> 6;
    const int wm = w >> 1, wn = w & 1;
    const int l16 = l & 15, lg = l >> 4;
    const int tc = N >> 7;
    const int bm = blockIdx.x / tc, bn = blockIdx.x % tc;
    const u16* Ab = A + (size_t)(bm << 7) * K;
    const u16* Bb = Bt + (size_t)(bn << 7) * K;

    f32x4 acc[4][4];
#pragma unroll
    for (int mi = 0; mi < 4; mi++)
#pragma unroll
        for (int ni = 0; ni < 4; ni++)
#pragma unroll
            for (int q = 0; q < 4; q++) acc[mi][ni][q] = 0.f;

    auto stage = [&](int buf, int k0) {
#pragma unroll
        for (int i = 0; i < 4; i++) {
            int s = tid + (i << 8);
            int ub = ((i << 8) + (w << 6)) << 3;
            gld16(Ab + (size_t)(s >> 3) * K + k0 + ((s & 7) << 3), &As[buf][ub]);
            gld16(Bb + (size_t)(s >> 3) * K + k0 + ((s & 7) << 3), &Bs[buf][ub]);
        }
    };

    stage(0, 0);
    int cur = 0;
    for (int k0 = 0; k0 < K; k0 += 64) {
        __syncthreads();
        if (k0 + 64 < K) stage(cur ^ 1, k0 + 64);
        const u16* Asc = As[cur];
        const u16* Bsc = Bs[cur];
#pragma unroll
        for (int kk = 0; kk < 2; kk++) {
            bf16x8 af[4], bfr[4];
#pragma unroll
            for (int mi = 0; mi < 4; mi++)
                af[mi] = *reinterpret_cast<const bf16x8*>(
                    &Asc[((wm << 6) + (mi << 4) + l16) * 64 + (kk << 5) + (lg << 3)]);
#pragma unroll
            for (int ni = 0; ni < 4; ni++)
                bfr[ni] = *reinterpret_cast<const bf16x8*>(
                    &Bsc[((wn << 6) + (ni << 4) + l16) * 64 + (kk << 5) + (lg << 3)]);
#pragma unroll
            for (int mi = 0; mi < 4; mi++)
#pragma unroll
                for (int ni = 0; ni < 4; ni++)
                    acc[mi][ni] = __builtin_amdgcn_mfma_f32_16x16x32_bf16(af[mi], bfr[ni], acc[mi][ni], 0, 0, 0);
        }
        cur ^= 1;
    }

    const int rb = (bm << 7) + (wm << 6), cb = (bn << 7) + (wn << 6);
    if constexpr (MODE == 0) {
        const int sec = cb >> 10;
#pragma unroll
        for (int ni = 0; ni < 4; ni++) {
            const int col = cb + (ni << 4) + l16;
            const float bb = bias[col];
            const int d = col & 1023, h = d >> 6, dh = d & 63;
#pragma unroll
            for (int mi = 0; mi < 4; mi++) {
                const int row0 = rb + (mi << 4) + (lg << 2);
                const int bidx = row0 >> 11, n0 = row0 & 2047;
                const size_t base = (size_t)(bidx * 16 + h) * 131072;
                if (sec == 0) {
#pragma unroll
                    for (int r = 0; r < 4; r++)
                        Qp[base + (size_t)(n0 + r) * 64 + dh] = f2bf(acc[mi][ni][r] + bb);
                } else if (sec == 1) {
#pragma unroll
                    for (int r = 0; r < 4; r++)
                        Kp[base + (size_t)(n0 + r) * 64 + dh] = f2bf((acc[mi][ni][r] + bb) * KSCALE);
                } else {
                    u16x4 pk;
#pragma unroll
                    for (int r = 0; r < 4; r++) pk[r] = f2bf(acc[mi][ni][r] + bb);
                    *reinterpret_cast<u16x4*>(&Vt[base + (size_t)dh * 2048 + n0]) = pk;
                }
            }
        }
    } else {
#pragma unroll
        for (int ni = 0; ni < 4; ni++) {
            const int col = cb + (ni << 4) + l16;
            const float bb = bias[col];
#pragma unroll
            for (int mi = 0; mi < 4; mi++)
#pragma unroll
                for (int r = 0; r < 4; r++) {
                    const int row = rb + (mi << 4) + (lg << 2) + r;
                    Cf[(size_t)row * N + col] = acc[mi][ni][r] + bb;
                }
        }
    }
}

// ---------------- flash attention: uniform 33-iter waves, no merge ----------------
// Wave task = pair (qt=p, qt=63-p): nt(p)+nt(63-p)=33 kv-iters exactly, for all p.
// Block = (bh, 4 consecutive p). 512 blocks x 4 waves = 2048 uniform waves.
__global__ __launch_bounds__(256, 2) void attn_k(const u16* __restrict__ Qp,
                                                 const u16* __restrict__ Kp,
                                                 const u16* __restrict__ Vt,
                                                 u16* __restrict__ Y) {
    __shared__ u16 P_lds[4][32 * 72];
    const int tid = threadIdx.x;
    const int l = tid & 63, w = tid >> 6;
    const int l16 = l & 15, lg = l >> 4;
    const int bh = blockIdx.x & 63;
    const int p = (blockIdx.x >> 6) * 4 + w;    // 0..31
    const int b = bh >> 4, h = bh & 15;
    const u16* Qb = Qp + (size_t)bh * 131072;
    const u16* Kb = Kp + (size_t)bh * 131072;
    const u16* Vb = Vt + (size_t)bh * 131072;
    u16* pl = &P_lds[w][0];

#pragma unroll 1
    for (int half = 0; half < 2; half++) {
        const int qt = half ? (63 - p) : p;
        const int nt = (qt >> 1) + 1;

        bf16x8 qf[2][2];
#pragma unroll
        for (int mi = 0; mi < 2; mi++)
#pragma unroll
            for (int kk = 0; kk < 2; kk++)
                qf[mi][kk] = *reinterpret_cast<const bf16x8*>(
                    Qb + (size_t)(qt * 32 + mi * 16 + l16) * 64 + kk * 32 + lg * 8);

        f32x4 o[2][4];
        float m_s[2] = {-1e30f, -1e30f};
        float l_s[2] = {0.f, 0.f};
#pragma unroll
        for (int mi = 0; mi < 2; mi++)
#pragma unroll
            for (int n = 0; n < 4; n++)
#pragma unroll
                for (int r = 0; r < 4; r++) o[mi][n][r] = 0.f;

        // preload K tile 0
        bf16x8 kf[4][2];
#pragma unroll
        for (int t = 0; t < 4; t++)
#pragma unroll
            for (int kk = 0; kk < 2; kk++)
                kf[t][kk] = *reinterpret_cast<const bf16x8*>(
                    Kb + (size_t)(t * 16 + l16) * 64 + kk * 32 + lg * 8);

#pragma unroll 1
        for (int it = 0; it < nt; it++) {
            const int kv0 = it << 6;
            const bool diag = (it == nt - 1);
            // issue V loads for THIS iter now (consumed at iter end)
            bf16x8 v0[4], v1[4];
#pragma unroll
            for (int n = 0; n < 4; n++) {
                const u16* vr = Vb + (size_t)(n * 16 + l16) * 2048 + kv0 + lg * 8;
                v0[n] = *reinterpret_cast<const bf16x8*>(vr);
                v1[n] = *reinterpret_cast<const bf16x8*>(vr + 32);
            }
            // QK^T (swapped operands -> S^T; lane owns q-row l16, 16 kv in-lane)
            float s4[2][4][4];
#pragma unroll
            for (int mi = 0; mi < 2; mi++)
#pragma unroll
                for (int t = 0; t < 4; t++) {
                    f32x4 s;
                    s[0] = s[1] = s[2] = s[3] = 0.f;
                    s = __builtin_amdgcn_mfma_f32_16x16x32_bf16(kf[t][0], qf[mi][0], s, 0, 0, 0);
                    s = __builtin_amdgcn_mfma_f32_16x16x32_bf16(kf[t][1], qf[mi][1], s, 0, 0, 0);
#pragma unroll
                    for (int r = 0; r < 4; r++) s4[mi][t][r] = s[r];
                }
            // reload K in place for NEXT iter (hidden under softmax+PV)
            {
                const int kvn = (it + 1 < nt) ? (kv0 + 64) : kv0;
#pragma unroll
                for (int t = 0; t < 4; t++)
#pragma unroll
                    for (int kk = 0; kk < 2; kk++)
                        kf[t][kk] = *reinterpret_cast<const bf16x8*>(
                            Kb + (size_t)(kvn + t * 16 + l16) * 64 + kk * 32 + lg * 8);
            }
#pragma unroll
            for (int mi = 0; mi < 2; mi++) {
                if (diag) {
                    const int qg = qt * 32 + mi * 16 + l16;
                    const int kvb = kv0 + lg * 4;
#pragma unroll
                    for (int t = 0; t < 4; t++)
#pragma unroll
                        for (int r = 0; r < 4; r++)
                            if (kvb + t * 16 + r > qg) s4[mi][t][r] = -1e30f;
                }
                float mt[4];
#pragma unroll
                for (int t = 0; t < 4; t++)
                    mt[t] = fmaxf(fmaxf(s4[mi][t][0], s4[mi][t][1]), fmaxf(s4[mi][t][2], s4[mi][t][3]));
                float mx = fmaxf(fmaxf(mt[0], mt[1]), fmaxf(mt[2], mt[3]));
                mx = fmaxf(mx, __shfl_xor(mx, 16, 64));
                mx = fmaxf(mx, __shfl_xor(mx, 32, 64));
                if (__any(mx - m_s[mi] > 8.0f)) {
                    float mn = fmaxf(m_s[mi], mx);
                    float al = __builtin_amdgcn_exp2f(m_s[mi] - mn);
                    m_s[mi] = mn;
                    l_s[mi] *= al;
#pragma unroll
                    for (int r = 0; r < 4; r++) {
                        float ar = __shfl(al, lg * 4 + r, 64);
#pragma unroll
                        for (int n = 0; n < 4; n++) o[mi][n][r] *= ar;
                    }
                }
#pragma unroll
                for (int t = 0; t < 4; t++)
#pragma unroll
                    for (int r = 0; r < 4; r++)
                        s4[mi][t][r] = __builtin_amdgcn_exp2f(s4[mi][t][r] - m_s[mi]);
                float st[4];
#pragma unroll
                for (int t = 0; t < 4; t++)
                    st[t] = (s4[mi][t][0] + s4[mi][t][1]) + (s4[mi][t][2] + s4[mi][t][3]);
                float sm = (st[0] + st[1]) + (st[2] + st[3]);
                sm += __shfl_xor(sm, 16, 64);
                sm += __shfl_xor(sm, 32, 64);
                l_s[mi] += sm;
                // pack P via v_cvt_pk_bf16_f32: 2 u32 per t -> one 8B store
#pragma unroll
                for (int t = 0; t < 4; t++) {
                    uint2 pk;
                    pk.x = cvt_pk_bf16(s4[mi][t][0], s4[mi][t][1]);
                    pk.y = cvt_pk_bf16(s4[mi][t][2], s4[mi][t][3]);
                    *reinterpret_cast<uint2*>(pl + (mi * 16 + l16) * 72 + t * 16 + lg * 4) = pk;
                }
            }
            bf16x8 pa[2][2];
#pragma unroll
            for (int mi = 0; mi < 2; mi++)
#pragma unroll
                for (int kk2 = 0; kk2 < 2; kk2++)
                    pa[mi][kk2] = *reinterpret_cast<const bf16x8*>(
                        pl + (mi * 16 + l16) * 72 + kk2 * 32 + lg * 8);
#pragma unroll
            for (int n = 0; n < 4; n++)
#pragma unroll
                for (int mi = 0; mi < 2; mi++) {
                    o[mi][n] = __builtin_amdgcn_mfma_f32_16x16x32_bf16(pa[mi][0], v0[n], o[mi][n], 0, 0, 0);
                    o[mi][n] = __builtin_amdgcn_mfma_f32_16x16x32_bf16(pa[mi][1], v1[n], o[mi][n], 0, 0, 0);
                }
        }
        // epilogue for this qt
#pragma unroll
        for (int mi = 0; mi < 2; mi++) {
#pragma unroll
            for (int r = 0; r < 4; r++) {
                const float li = __shfl(l_s[mi], lg * 4 + r, 64);
                const float inv = 1.0f / li;
                const size_t row = (size_t)(b * 2048 + qt * 32 + mi * 16 + lg * 4 + r);
#pragma unroll
                for (int n = 0; n < 4; n++)
                    Y[row * 1024 + h * 64 + n * 16 + l16] = f2bf(o[mi][n][r] * inv);
            }
        }
    }
}

extern "C" void kernel_launch(void* const* d_in, const int* in_sizes, int n_in,
                              void* d_out, int out_size, void* d_ws, size_t ws_size,
                              hipStream_t stream) {
    const float* x     = (const float*)d_in[0];
    const float* w_qkv = (const float*)d_in[1];
    const float* b_qkv = (const float*)d_in[2];
    const float* w_o   = (const float*)d_in[3];
    const float* b_o   = (const float*)d_in[4];
    float* out = (float*)d_out;

    u16* ws  = (u16*)d_ws;
    u16* xb  = ws;                 // [8192][1024] x bf16; reused as attention output Y
    u16* wqT = ws + 8388608;       // [3072][1024]
    u16* woT = ws + 11534336;      // [1024][1024]
    u16* Qp  = ws + 12582912;      // [64 bh][2048][64]
    u16* Kp  = ws + 20971520;      // [64 bh][2048][64] (pre-scaled by 0.125*log2e)
    u16* Vt  = ws + 29360128;      // [64 bh][64][2048]

    cvt_f32_bf16_k<<<4096, 256, 0, stream>>>(x, xb, 1048576);
    tr_f32_bf16_k<<<768, 256, 0, stream>>>(w_qkv, wqT, 1024, 3072);
    tr_f32_bf16_k<<<256, 256, 0, stream>>>(w_o, woT, 1024, 1024);
    gemm_bt_k<0><<<1536, 256, 0, stream>>>(xb, wqT, b_qkv, Qp, Kp, Vt, nullptr, 8192, 3072, 1024);
    attn_k<<<512, 256, 0, stream>>>(Qp, Kp, Vt, xb);
    gemm_bt_k<1><<<512, 256, 0, stream>>>(xb, woT, b_o, nullptr, nullptr, nullptr, out, 8192, 1024, 1024);
}